// Round 2
// baseline (1032.035 us; speedup 1.0000x reference)
//
#include <hip/hip_runtime.h>

#define GI  1220          // g_i feature dim
#define KP  1280          // K padded to 40 * 32
#define BK  128           // K-chunk
#define NCH (KP / BK)     // 10 chunks
#define NP  192           // hidden dim padded 150 -> 192 (12 * 16)
#define ABW 320           // AB row: A[0:160) | B[160:320), cols >=150 zero

typedef _Float16      f16;
typedef _Float16      f16x8 __attribute__((ext_vector_type(8)));
typedef float         f32x4 __attribute__((ext_vector_type(4)));
typedef unsigned int  u32x4 __attribute__((ext_vector_type(4)));
typedef unsigned int  u32x2 __attribute__((ext_vector_type(2)));

__device__ __forceinline__ unsigned short f2h(float f) {
  return __builtin_bit_cast(unsigned short, (f16)f);
}
__device__ __forceinline__ float h2f(unsigned short u) {
  return (float)__builtin_bit_cast(f16, u);
}
__device__ __forceinline__ unsigned int pkh(float a, float b) {
  return (unsigned int)f2h(a) | ((unsigned int)f2h(b) << 16);
}

// ---------------------------------------------------------------------------
// g2h: streaming f32 -> f16 conversion of g into zero-padded gb[N][KP].
// Pure BW-bound: coalesced 32B reads, 16B writes.
// ---------------------------------------------------------------------------
__global__ void g2h_kernel(const float* __restrict__ g, unsigned short* __restrict__ gb,
                           int N) {
  int idx = blockIdx.x * 256 + threadIdx.x;
  if (idx >= N * (KP / 8)) return;
  int row = idx / (KP / 8);
  int k = (idx % (KP / 8)) * 8;
  const float* gr = g + (long)row * GI + k;
  u32x4 o;
  if (k + 8 <= GI) {
    f32x4 a = *(const f32x4*)gr;
    f32x4 b = *(const f32x4*)(gr + 4);
    o.x = pkh(a.x, a.y); o.y = pkh(a.z, a.w);
    o.z = pkh(b.x, b.y); o.w = pkh(b.z, b.w);
  } else if (k < GI) {            // k == 1216: 4 real elems + 4 zeros
    f32x4 a = *(const f32x4*)gr;
    o.x = pkh(a.x, a.y); o.y = pkh(a.z, a.w);
    o.z = 0u; o.w = 0u;
  } else {
    o.x = 0u; o.y = 0u; o.z = 0u; o.w = 0u;
  }
  *(u32x4*)(gb + (long)row * KP + k) = o;
}

// ---------------------------------------------------------------------------
// prep: build f16 transposed weight layouts + fp32 proj tables in ws.
//  W1ab_t [320][KP]  n-major, k-contig:  n<150 -> W1a col n ; 160<=n<310 -> W1b col n-160
//  W1c_t  [192][KP]  n-major, k-contig:  W1 rows 2440..3659
//  W2_t   [192][192] n-major, k-contig
//  projs  [20][192]  fp32: rows 0..8 dist (+b1 folded), 9..16 genre, 17..19 speaker
// ---------------------------------------------------------------------------
__global__ void prep_kernel(const float* __restrict__ W1, const float* __restrict__ W2,
                            const float* __restrict__ b1,
                            const float* __restrict__ de, const float* __restrict__ ge,
                            const float* __restrict__ se,
                            unsigned short* __restrict__ W1ab_t,
                            unsigned short* __restrict__ W1c_t,
                            unsigned short* __restrict__ W2_t,
                            float* __restrict__ projs) {
  int idx = blockIdx.x * 256 + threadIdx.x;
  const int R1 = ABW * KP, R2 = NP * KP, R3 = NP * NP, R4 = 20 * NP;
  if (idx < R1) {
    int n = idx / KP, k = idx % KP;
    float v = 0.f;
    if (k < GI) {
      if (n < 150)                 v = W1[k * 150 + n];
      else if (n >= 160 && n < 310) v = W1[(GI + k) * 150 + (n - 160)];
    }
    W1ab_t[idx] = f2h(v);
    return;
  }
  idx -= R1;
  if (idx < R2) {
    int n = idx / KP, k = idx % KP;
    float v = (k < GI && n < 150) ? W1[(2 * GI + k) * 150 + n] : 0.f;
    W1c_t[idx] = f2h(v);
    return;
  }
  idx -= R2;
  if (idx < R3) {
    int n = idx / NP, k = idx % NP;
    float v = (n < 150 && k < 150) ? W2[k * 150 + n] : 0.f;
    W2_t[idx] = f2h(v);
    return;
  }
  idx -= R3;
  if (idx < R4) {
    int r = idx / NP, n = idx % NP;
    float v = 0.f;
    if (n < 150) {
      if (r < 9) {
        v = b1[n];
        for (int t = 0; t < 20; ++t) v += de[r * 20 + t] * W1[(3660 + t) * 150 + n];
      } else if (r < 17) {
        int q = r - 9;
        for (int t = 0; t < 20; ++t) v += ge[q * 20 + t] * W1[(3680 + t) * 150 + n];
      } else {
        int q = r - 17;
        for (int t = 0; t < 20; ++t) v += se[q * 20 + t] * W1[(3700 + t) * 150 + n];
      }
    }
    projs[idx] = v;
  }
}

// ---------------------------------------------------------------------------
// ab_kernel:  AB[m][0:160) = (G @ W1a)[m],  AB[m][160:320) = (G @ W1b)[m], f16.
// Reads gb (f16): staging is a pure 64B/thread copy. Double-buffered LDS,
// one barrier per K-chunk (T3-minimum 2-phase).
// ---------------------------------------------------------------------------
__global__ __launch_bounds__(256, 3)
void ab_kernel(const unsigned short* __restrict__ gb,
               const unsigned short* __restrict__ W1ab_t,
               unsigned short* __restrict__ AB, int N) {
  __shared__ __attribute__((aligned(16))) unsigned short sX[2][64 * 136];
  const int t = threadIdx.x;
  const int m0 = blockIdx.x * 64;
  const int w = t >> 6, lane = t & 63, quad = lane >> 4, lm = lane & 15;

  f32x4 acc[4][5];
#pragma unroll
  for (int a = 0; a < 4; ++a)
#pragma unroll
    for (int b = 0; b < 5; ++b) { acc[a][b].x = 0.f; acc[a][b].y = 0.f; acc[a][b].z = 0.f; acc[a][b].w = 0.f; }

  const int r = t >> 2, s = t & 3;
  int row = m0 + r; if (row >= N) row = N - 1;
  const unsigned short* gr = gb + (long)row * KP;

  // stage chunk 0
#pragma unroll
  for (int q = 0; q < 4; ++q)
    *(u32x4*)&sX[0][r * 136 + s * 32 + q * 8] = *(const u32x4*)(gr + s * 32 + q * 8);
  __syncthreads();

  for (int c = 0; c < NCH; ++c) {
    const int cur = c & 1;
    if (c + 1 < NCH) {
#pragma unroll
      for (int q = 0; q < 4; ++q)
        *(u32x4*)&sX[cur ^ 1][r * 136 + s * 32 + q * 8] =
            *(const u32x4*)(gr + (c + 1) * BK + s * 32 + q * 8);
    }
#pragma unroll
    for (int kk = 0; kk < 4; ++kk) {
      f16x8 af[4];
#pragma unroll
      for (int mi = 0; mi < 4; ++mi)
        af[mi] = *(const f16x8*)&sX[cur][(mi * 16 + lm) * 136 + kk * 32 + quad * 8];
#pragma unroll
      for (int tl = 0; tl < 5; ++tl) {
        int n = (w * 5 + tl) * 16 + lm;
        f16x8 bfr = *(const f16x8*)(W1ab_t + n * KP + c * BK + kk * 32 + quad * 8);
#pragma unroll
        for (int mi = 0; mi < 4; ++mi)
          acc[mi][tl] = __builtin_amdgcn_mfma_f32_16x16x32_f16(af[mi], bfr, acc[mi][tl], 0, 0, 0);
      }
    }
    __syncthreads();
  }
#pragma unroll
  for (int mi = 0; mi < 4; ++mi)
#pragma unroll
    for (int reg = 0; reg < 4; ++reg) {
      int m = m0 + mi * 16 + quad * 4 + reg;
      if (m < N) {
#pragma unroll
        for (int tl = 0; tl < 5; ++tl) {
          int n = (w * 5 + tl) * 16 + lm;
          AB[(long)m * ABW + n] = f2h(acc[mi][tl][reg]);
        }
      }
    }
}

// ---------------------------------------------------------------------------
// pair_kernel layer-1 helpers: register-resident A fragments, 2-deep pipeline.
// ---------------------------------------------------------------------------
__device__ __forceinline__ void pref(const unsigned short* pm, const unsigned short* pa,
                                     int ko, f16x8 (&xm)[4], f16x8 (&xa)[4]) {
#pragma unroll
  for (int kk = 0; kk < 4; ++kk) {
    xm[kk] = *(const f16x8*)(pm + ko + kk * 32);
    xa[kk] = *(const f16x8*)(pa + ko + kk * 32);
  }
}
__device__ __forceinline__ void comp(const unsigned short* __restrict__ W1c_t, int lm, int ko,
                                     f16x8 (&xm)[4], f16x8 (&xa)[4], f32x4 (&acc)[12]) {
#pragma unroll
  for (int kk = 0; kk < 4; ++kk) {
    f16x8 af = xm[kk] * xa[kk];
#pragma unroll
    for (int tl = 0; tl < 12; ++tl) {
      f16x8 bf = *(const f16x8*)(W1c_t + (tl * 16 + lm) * KP + ko + kk * 32);
      acc[tl] = __builtin_amdgcn_mfma_f32_16x16x32_f16(af, bf, acc[tl], 0, 0, 0);
    }
  }
}

// ---------------------------------------------------------------------------
// pair_kernel: fused per 64 pairs. Layer 1 is barrier-free: wave w owns pair
// rows w*16+lm, all 12 n-tiles; A fragments gathered straight into registers
// (one 16B load per operand) with a 2-deep chunk pipeline. Only 4 barriers.
// ---------------------------------------------------------------------------
__global__ __launch_bounds__(256, 3)
void pair_kernel(const unsigned short* __restrict__ gb, const float* __restrict__ msc,
                 const unsigned short* __restrict__ AB,
                 const unsigned short* __restrict__ W1c_t,
                 const unsigned short* __restrict__ W2_t,
                 const float* __restrict__ projs,
                 const float* __restrict__ b2, const float* __restrict__ W3,
                 const float* __restrict__ b3,
                 const int* __restrict__ mid, const int* __restrict__ aid,
                 const int* __restrict__ did, const int* __restrict__ gid,
                 const int* __restrict__ sid,
                 float* __restrict__ out, int N, int P) {
  __shared__ __attribute__((aligned(16))) unsigned short sH1[64 * 200];   // h1
  __shared__ __attribute__((aligned(16))) unsigned short sBias[64 * NP];  // bias, then h2
  __shared__ int sM[64], sA[64], sD[64], sG[64], sS[64];
  __shared__ float sScore[64];

  const int t = threadIdx.x;
  const int p0 = blockIdx.x * 64;
  const int w = t >> 6, lane = t & 63, quad = lane >> 4, lm = lane & 15;

  if (t < 64) {
    int p = p0 + t;
    int m_ = 0, a_ = 0, d_ = 0, g_ = 0, s_ = 0;
    float sc = 0.f;
    if (p < P) {
      m_ = mid[p]; a_ = aid[p]; d_ = did[p]; g_ = gid[p]; s_ = sid[p];
      sc = msc[m_] + msc[a_];
    }
    sM[t] = m_; sA[t] = a_; sD[t] = d_; sG[t] = g_; sS[t] = s_;
    sScore[t] = sc;
  }
  __syncthreads();

  const int r = t >> 2, s = t & 3;

  // ---- bias tile: bias[m][n] = A[mid][n] + B[aid][n] + dist+genre+speaker proj (b1 folded)
  {
    const unsigned short* Ar = AB + (long)sM[r] * ABW;
    const unsigned short* Br = AB + (long)sA[r] * ABW + 160;
    const float* dp = projs + sD[r] * NP;
    const float* gp = projs + (9 + sG[r]) * NP;
    const float* sp = projs + (17 + sS[r]) * NP;
#pragma unroll
    for (int j = 0; j < 6; ++j) {
      int n = s * 48 + j * 8;
      f32x4 p0v = *(const f32x4*)(dp + n) + *(const f32x4*)(gp + n) + *(const f32x4*)(sp + n);
      f32x4 p1v = *(const f32x4*)(dp + n + 4) + *(const f32x4*)(gp + n + 4) + *(const f32x4*)(sp + n + 4);
      if (n < 160) {
        u32x4 a8 = *(const u32x4*)(Ar + n);
        u32x4 b8 = *(const u32x4*)(Br + n);
        p0v.x += h2f((unsigned short)(a8.x & 0xffff)) + h2f((unsigned short)(b8.x & 0xffff));
        p0v.y += h2f((unsigned short)(a8.x >> 16))    + h2f((unsigned short)(b8.x >> 16));
        p0v.z += h2f((unsigned short)(a8.y & 0xffff)) + h2f((unsigned short)(b8.y & 0xffff));
        p0v.w += h2f((unsigned short)(a8.y >> 16))    + h2f((unsigned short)(b8.y >> 16));
        p1v.x += h2f((unsigned short)(a8.z & 0xffff)) + h2f((unsigned short)(b8.z & 0xffff));
        p1v.y += h2f((unsigned short)(a8.z >> 16))    + h2f((unsigned short)(b8.z >> 16));
        p1v.z += h2f((unsigned short)(a8.w & 0xffff)) + h2f((unsigned short)(b8.w & 0xffff));
        p1v.w += h2f((unsigned short)(a8.w >> 16))    + h2f((unsigned short)(b8.w >> 16));
      }
      u32x4 o;
      o.x = pkh(p0v.x, p0v.y); o.y = pkh(p0v.z, p0v.w);
      o.z = pkh(p1v.x, p1v.y); o.w = pkh(p1v.z, p1v.w);
      *(u32x4*)&sBias[r * NP + n] = o;
    }
  }

  // ---- layer 1: wave w owns pair rows w*16+lm; acc over all 12 n-tiles.
  const int prow = w * 16 + lm;
  const unsigned short* pm = gb + (long)sM[prow] * KP;
  const unsigned short* pa = gb + (long)sA[prow] * KP;

  f32x4 acc[12];
#pragma unroll
  for (int tl = 0; tl < 12; ++tl) { acc[tl].x = 0.f; acc[tl].y = 0.f; acc[tl].z = 0.f; acc[tl].w = 0.f; }

  const int qo = quad * 8;
  f16x8 xm0[4], xa0[4], xm1[4], xa1[4];
  pref(pm, pa, qo, xm0, xa0);
#pragma unroll
  for (int c = 0; c < NCH; c += 2) {
    if (c + 1 < NCH) pref(pm, pa, (c + 1) * BK + qo, xm1, xa1);
    comp(W1c_t, lm, c * BK + qo, xm0, xa0, acc);
    if (c + 2 < NCH) pref(pm, pa, (c + 2) * BK + qo, xm0, xa0);
    if (c + 1 < NCH) comp(W1c_t, lm, (c + 1) * BK + qo, xm1, xa1, acc);
  }

  // ---- epilogue 1: + bias, relu, h1 -> LDS (stride 200)
  __syncthreads();   // sBias complete (cross-wave) before reads
#pragma unroll
  for (int tl = 0; tl < 12; ++tl) {
    int n = tl * 16 + lm;
#pragma unroll
    for (int reg = 0; reg < 4; ++reg) {
      int m = w * 16 + quad * 4 + reg;
      float v = acc[tl][reg] + h2f(sBias[m * NP + n]);
      v = fmaxf(v, 0.f);
      sH1[m * 200 + n] = f2h(v);
    }
  }
  __syncthreads();

  // ---- layer 2: h1[64][192] @ W2_t (wave w -> 3 n-tiles, all 4 row groups)
  f32x4 acc2[4][3];
#pragma unroll
  for (int a = 0; a < 4; ++a)
#pragma unroll
    for (int b = 0; b < 3; ++b) { acc2[a][b].x = 0.f; acc2[a][b].y = 0.f; acc2[a][b].z = 0.f; acc2[a][b].w = 0.f; }
#pragma unroll
  for (int kk = 0; kk < 6; ++kk) {
    f16x8 af[4];
#pragma unroll
    for (int mi = 0; mi < 4; ++mi)
      af[mi] = *(const f16x8*)&sH1[(mi * 16 + lm) * 200 + kk * 32 + qo];
#pragma unroll
    for (int tl = 0; tl < 3; ++tl) {
      int n = (w * 3 + tl) * 16 + lm;
      f16x8 bfr = *(const f16x8*)(W2_t + n * NP + kk * 32 + qo);
#pragma unroll
      for (int mi = 0; mi < 4; ++mi)
        acc2[mi][tl] = __builtin_amdgcn_mfma_f32_16x16x32_f16(af[mi], bfr, acc2[mi][tl], 0, 0, 0);
    }
  }

  // ---- epilogue 2: + b2, relu, h2 -> sBias region (stride NP)
#pragma unroll
  for (int mi = 0; mi < 4; ++mi)
#pragma unroll
    for (int tl = 0; tl < 3; ++tl) {
      int n = (w * 3 + tl) * 16 + lm;
      float bb = (n < 150) ? b2[n] : 0.f;
#pragma unroll
      for (int reg = 0; reg < 4; ++reg) {
        int m = mi * 16 + quad * 4 + reg;
        float v = acc2[mi][tl][reg] + bb;
        v = fmaxf(v, 0.f);
        sBias[m * NP + n] = f2h(v);
      }
    }
  __syncthreads();

  // ---- layer 3: pairwise = h2 . W3 ; sij = ms_i + ms_j + pairwise + b3
  {
    float sum = 0.f;
#pragma unroll
    for (int j = 0; j < 48; ++j) {
      int n = s * 48 + j;
      if (n < 150) sum += h2f(sBias[r * NP + n]) * W3[n];
    }
    sum += __shfl_xor(sum, 1);
    sum += __shfl_xor(sum, 2);
    if (s == 0) {
      int p = p0 + r;
      if (p < P) out[p] = sScore[r] + sum + b3[0];
    }
  }
}

extern "C" void kernel_launch(void* const* d_in, const int* in_sizes, int n_in,
                              void* d_out, int out_size, void* d_ws, size_t ws_size,
                              hipStream_t stream) {
  (void)n_in; (void)out_size; (void)ws_size;
  const float* g   = (const float*)d_in[0];
  const float* msc = (const float*)d_in[1];
  const float* de  = (const float*)d_in[2];
  const float* ge  = (const float*)d_in[3];
  const float* se  = (const float*)d_in[4];
  const float* W1  = (const float*)d_in[5];
  const float* b1  = (const float*)d_in[6];
  const float* W2  = (const float*)d_in[7];
  const float* b2  = (const float*)d_in[8];
  const float* W3  = (const float*)d_in[9];
  const float* b3  = (const float*)d_in[10];
  const int* mid = (const int*)d_in[11];
  const int* aid = (const int*)d_in[12];
  const int* did = (const int*)d_in[13];
  const int* gid = (const int*)d_in[14];
  const int* sid = (const int*)d_in[15];
  const int N = in_sizes[0] / GI;
  const int P = in_sizes[11];
  float* out = (float*)d_out;

  char* ws = (char*)d_ws;
  size_t off = 0;
  auto alloc = [&](size_t bytes) { char* p = ws + off; off = (off + bytes + 255) & ~(size_t)255; return p; };
  unsigned short* gb     = (unsigned short*)alloc((size_t)N * KP * 2);   // 128 MB f16 copy of g
  unsigned short* AB     = (unsigned short*)alloc((size_t)N * ABW * 2);
  unsigned short* W1ab_t = (unsigned short*)alloc((size_t)ABW * KP * 2);
  unsigned short* W1c_t  = (unsigned short*)alloc((size_t)NP * KP * 2);
  unsigned short* W2_t   = (unsigned short*)alloc((size_t)NP * NP * 2);
  float* projs           = (float*)alloc((size_t)20 * NP * 4);

  const int prep_total = ABW * KP + NP * KP + NP * NP + 20 * NP;
  prep_kernel<<<(prep_total + 255) / 256, 256, 0, stream>>>(W1, W2, b1, de, ge, se,
                                                            W1ab_t, W1c_t, W2_t, projs);
  g2h_kernel<<<(N * (KP / 8) + 255) / 256, 256, 0, stream>>>(g, gb, N);
  ab_kernel<<<(N + 63) / 64, 256, 0, stream>>>(gb, W1ab_t, AB, N);
  pair_kernel<<<(P + 63) / 64, 256, 0, stream>>>(gb, msc, AB, W1c_t, W2_t, projs,
                                                 b2, W3, b3, mid, aid, did, gid, sid,
                                                 out, N, P);
}

// Round 3
// 730.832 us; speedup vs baseline: 1.4121x; 1.4121x over previous
//
#include <hip/hip_runtime.h>

#define GI  1220          // g_i feature dim
#define KP  1280          // K padded to 40 * 32
#define BK  128           // K-chunk
#define NCH (KP / BK)     // 10 chunks
#define NP  192           // hidden dim padded 150 -> 192 (12 * 16)
#define ABW 320           // AB row: A[0:160) | B[160:320), cols >=150 zero

typedef _Float16      f16;
typedef _Float16      f16x8 __attribute__((ext_vector_type(8)));
typedef float         f32x4 __attribute__((ext_vector_type(4)));
typedef unsigned int  u32x4 __attribute__((ext_vector_type(4)));
typedef unsigned int  u32x2 __attribute__((ext_vector_type(2)));

__device__ __forceinline__ unsigned short f2h(float f) {
  return __builtin_bit_cast(unsigned short, (f16)f);
}
__device__ __forceinline__ float h2f(unsigned short u) {
  return (float)__builtin_bit_cast(f16, u);
}
__device__ __forceinline__ unsigned int pkh(float a, float b) {
  return (unsigned int)f2h(a) | ((unsigned int)f2h(b) << 16);
}

// ---------------------------------------------------------------------------
// g2h: streaming f32 -> f16 conversion of g into zero-padded gb[N][KP].
// ---------------------------------------------------------------------------
__global__ void g2h_kernel(const float* __restrict__ g, unsigned short* __restrict__ gb,
                           int N) {
  int idx = blockIdx.x * 256 + threadIdx.x;
  if (idx >= N * (KP / 8)) return;
  int row = idx / (KP / 8);
  int k = (idx % (KP / 8)) * 8;
  const float* gr = g + (long)row * GI + k;
  u32x4 o;
  if (k + 8 <= GI) {
    f32x4 a = *(const f32x4*)gr;
    f32x4 b = *(const f32x4*)(gr + 4);
    o.x = pkh(a.x, a.y); o.y = pkh(a.z, a.w);
    o.z = pkh(b.x, b.y); o.w = pkh(b.z, b.w);
  } else if (k < GI) {            // k == 1216: 4 real elems + 4 zeros
    f32x4 a = *(const f32x4*)gr;
    o.x = pkh(a.x, a.y); o.y = pkh(a.z, a.w);
    o.z = 0u; o.w = 0u;
  } else {
    o.x = 0u; o.y = 0u; o.z = 0u; o.w = 0u;
  }
  *(u32x4*)(gb + (long)row * KP + k) = o;
}

// ---------------------------------------------------------------------------
// prep: build f16 transposed weight layouts + fp32 proj tables in ws.
// ---------------------------------------------------------------------------
__global__ void prep_kernel(const float* __restrict__ W1, const float* __restrict__ W2,
                            const float* __restrict__ b1,
                            const float* __restrict__ de, const float* __restrict__ ge,
                            const float* __restrict__ se,
                            unsigned short* __restrict__ W1ab_t,
                            unsigned short* __restrict__ W1c_t,
                            unsigned short* __restrict__ W2_t,
                            float* __restrict__ projs) {
  int idx = blockIdx.x * 256 + threadIdx.x;
  const int R1 = ABW * KP, R2 = NP * KP, R3 = NP * NP, R4 = 20 * NP;
  if (idx < R1) {
    int n = idx / KP, k = idx % KP;
    float v = 0.f;
    if (k < GI) {
      if (n < 150)                 v = W1[k * 150 + n];
      else if (n >= 160 && n < 310) v = W1[(GI + k) * 150 + (n - 160)];
    }
    W1ab_t[idx] = f2h(v);
    return;
  }
  idx -= R1;
  if (idx < R2) {
    int n = idx / KP, k = idx % KP;
    float v = (k < GI && n < 150) ? W1[(2 * GI + k) * 150 + n] : 0.f;
    W1c_t[idx] = f2h(v);
    return;
  }
  idx -= R2;
  if (idx < R3) {
    int n = idx / NP, k = idx % NP;
    float v = (n < 150 && k < 150) ? W2[k * 150 + n] : 0.f;
    W2_t[idx] = f2h(v);
    return;
  }
  idx -= R3;
  if (idx < R4) {
    int r = idx / NP, n = idx % NP;
    float v = 0.f;
    if (n < 150) {
      if (r < 9) {
        v = b1[n];
        for (int t = 0; t < 20; ++t) v += de[r * 20 + t] * W1[(3660 + t) * 150 + n];
      } else if (r < 17) {
        int q = r - 9;
        for (int t = 0; t < 20; ++t) v += ge[q * 20 + t] * W1[(3680 + t) * 150 + n];
      } else {
        int q = r - 17;
        for (int t = 0; t < 20; ++t) v += se[q * 20 + t] * W1[(3700 + t) * 150 + n];
      }
    }
    projs[idx] = v;
  }
}

// ---------------------------------------------------------------------------
// ab_kernel:  AB[m][0:160) = (G @ W1a)[m],  AB[m][160:320) = (G @ W1b)[m], f16.
// T14 async-stage: issue chunk c+1 loads into regs BEFORE MFMA of chunk c,
// ds_write after; double-buffered LDS, one barrier per chunk.
// ---------------------------------------------------------------------------
__global__ __launch_bounds__(256, 3)
void ab_kernel(const unsigned short* __restrict__ gb,
               const unsigned short* __restrict__ W1ab_t,
               unsigned short* __restrict__ AB, int N) {
  __shared__ __attribute__((aligned(16))) unsigned short sX[2][64 * 136];
  const int t = threadIdx.x;
  const int m0 = blockIdx.x * 64;
  const int w = t >> 6, lane = t & 63, quad = lane >> 4, lm = lane & 15;

  f32x4 acc[4][5];
#pragma unroll
  for (int a = 0; a < 4; ++a)
#pragma unroll
    for (int b = 0; b < 5; ++b) { acc[a][b].x = 0.f; acc[a][b].y = 0.f; acc[a][b].z = 0.f; acc[a][b].w = 0.f; }

  const int r = t >> 2, s = t & 3;
  int row = m0 + r; if (row >= N) row = N - 1;
  const unsigned short* gr = gb + (long)row * KP;

  u32x4 xr[4];
  auto loadx = [&](int c) {
#pragma unroll
    for (int q = 0; q < 4; ++q)
      xr[q] = *(const u32x4*)(gr + c * BK + s * 32 + q * 8);
  };
  auto storex = [&](int buf) {
#pragma unroll
    for (int q = 0; q < 4; ++q)
      *(u32x4*)&sX[buf][r * 136 + s * 32 + q * 8] = xr[q];
  };

  loadx(0);
  storex(0);
  __syncthreads();

  for (int c = 0; c < NCH; ++c) {
    const int cur = c & 1;
    if (c + 1 < NCH) loadx(c + 1);            // issue early (T14)
#pragma unroll
    for (int kk = 0; kk < 4; ++kk) {
      f16x8 af[4];
#pragma unroll
      for (int mi = 0; mi < 4; ++mi)
        af[mi] = *(const f16x8*)&sX[cur][(mi * 16 + lm) * 136 + kk * 32 + quad * 8];
#pragma unroll
      for (int tl = 0; tl < 5; ++tl) {
        int n = (w * 5 + tl) * 16 + lm;
        f16x8 bfr = *(const f16x8*)(W1ab_t + n * KP + c * BK + kk * 32 + quad * 8);
#pragma unroll
        for (int mi = 0; mi < 4; ++mi)
          acc[mi][tl] = __builtin_amdgcn_mfma_f32_16x16x32_f16(af[mi], bfr, acc[mi][tl], 0, 0, 0);
      }
    }
    if (c + 1 < NCH) storex(cur ^ 1);         // write late
    __syncthreads();
  }

#pragma unroll
  for (int mi = 0; mi < 4; ++mi)
#pragma unroll
    for (int reg = 0; reg < 4; ++reg) {
      int m = m0 + mi * 16 + quad * 4 + reg;
      if (m < N) {
#pragma unroll
        for (int tl = 0; tl < 5; ++tl) {
          int n = (w * 5 + tl) * 16 + lm;
          AB[(long)m * ABW + n] = f2h(acc[mi][tl][reg]);
        }
      }
    }
}

// ---------------------------------------------------------------------------
// pair_kernel: fused per 64 pairs. Layer 1: LDS-staged product (mi-reused B),
// ping-pong register prefetch of the gathered rows (issue chunk c+1's loads
// before barrier+store+MFMA of chunk c).
// ---------------------------------------------------------------------------
__global__ __launch_bounds__(256, 3)
void pair_kernel(const unsigned short* __restrict__ gb, const float* __restrict__ msc,
                 const unsigned short* __restrict__ AB,
                 const unsigned short* __restrict__ W1c_t,
                 const unsigned short* __restrict__ W2_t,
                 const float* __restrict__ projs,
                 const float* __restrict__ b2, const float* __restrict__ W3,
                 const float* __restrict__ b3,
                 const int* __restrict__ mid, const int* __restrict__ aid,
                 const int* __restrict__ did, const int* __restrict__ gid,
                 const int* __restrict__ sid,
                 float* __restrict__ out, int N, int P) {
  __shared__ __attribute__((aligned(16))) unsigned short sXh1[64 * 200];  // X stage (stride 136) / h1 (stride 200)
  __shared__ __attribute__((aligned(16))) unsigned short sBias[64 * NP];  // bias (then h2)
  __shared__ int sM[64], sA[64], sD[64], sG[64], sS[64];
  __shared__ float sScore[64];

  const int t = threadIdx.x;
  const int p0 = blockIdx.x * 64;
  const int w = t >> 6, lane = t & 63, quad = lane >> 4, lm = lane & 15;

  if (t < 64) {
    int p = p0 + t;
    int m_ = 0, a_ = 0, d_ = 0, g_ = 0, s_ = 0;
    float sc = 0.f;
    if (p < P) {
      m_ = mid[p]; a_ = aid[p]; d_ = did[p]; g_ = gid[p]; s_ = sid[p];
      sc = msc[m_] + msc[a_];
    }
    sM[t] = m_; sA[t] = a_; sD[t] = d_; sG[t] = g_; sS[t] = s_;
    sScore[t] = sc;
  }
  __syncthreads();

  const int r = t >> 2, s = t & 3;
  const unsigned short* gbm = gb + (long)sM[r] * KP;
  const unsigned short* gba = gb + (long)sA[r] * KP;

  // ---- bias tile: bias[m][n] = A[mid][n] + B[aid][n] + dist+genre+speaker proj (b1 folded)
  {
    const unsigned short* Ar = AB + (long)sM[r] * ABW;
    const unsigned short* Br = AB + (long)sA[r] * ABW + 160;
    const float* dp = projs + sD[r] * NP;
    const float* gp = projs + (9 + sG[r]) * NP;
    const float* sp = projs + (17 + sS[r]) * NP;
#pragma unroll
    for (int j = 0; j < 6; ++j) {
      int n = s * 48 + j * 8;
      f32x4 p0v = *(const f32x4*)(dp + n) + *(const f32x4*)(gp + n) + *(const f32x4*)(sp + n);
      f32x4 p1v = *(const f32x4*)(dp + n + 4) + *(const f32x4*)(gp + n + 4) + *(const f32x4*)(sp + n + 4);
      if (n < 160) {
        u32x4 a8 = *(const u32x4*)(Ar + n);
        u32x4 b8 = *(const u32x4*)(Br + n);
        p0v.x += h2f((unsigned short)(a8.x & 0xffff)) + h2f((unsigned short)(b8.x & 0xffff));
        p0v.y += h2f((unsigned short)(a8.x >> 16))    + h2f((unsigned short)(b8.x >> 16));
        p0v.z += h2f((unsigned short)(a8.y & 0xffff)) + h2f((unsigned short)(b8.y & 0xffff));
        p0v.w += h2f((unsigned short)(a8.y >> 16))    + h2f((unsigned short)(b8.y >> 16));
        p1v.x += h2f((unsigned short)(a8.z & 0xffff)) + h2f((unsigned short)(b8.z & 0xffff));
        p1v.y += h2f((unsigned short)(a8.z >> 16))    + h2f((unsigned short)(b8.z >> 16));
        p1v.z += h2f((unsigned short)(a8.w & 0xffff)) + h2f((unsigned short)(b8.w & 0xffff));
        p1v.w += h2f((unsigned short)(a8.w >> 16))    + h2f((unsigned short)(b8.w >> 16));
      }
      u32x4 o;
      o.x = pkh(p0v.x, p0v.y); o.y = pkh(p0v.z, p0v.w);
      o.z = pkh(p1v.x, p1v.y); o.w = pkh(p1v.z, p1v.w);
      *(u32x4*)&sBias[r * NP + n] = o;
    }
  }

  // ---- layer 1 bilinear over K=1280, chunked BK=128, ping-pong reg prefetch
  f32x4 acc[4][3];
#pragma unroll
  for (int a = 0; a < 4; ++a)
#pragma unroll
    for (int b = 0; b < 3; ++b) { acc[a][b].x = 0.f; acc[a][b].y = 0.f; acc[a][b].z = 0.f; acc[a][b].w = 0.f; }

  u32x4 xm0[4], xa0[4], xm1[4], xa1[4];
  auto loadc = [&](int c, u32x4 (&xm)[4], u32x4 (&xa)[4]) {
#pragma unroll
    for (int i = 0; i < 4; ++i) {
      xm[i] = *(const u32x4*)(gbm + c * BK + i * 32 + s * 8);
      xa[i] = *(const u32x4*)(gba + c * BK + i * 32 + s * 8);
    }
  };
  auto storec = [&](u32x4 (&xm)[4], u32x4 (&xa)[4]) {
#pragma unroll
    for (int i = 0; i < 4; ++i) {
      f16x8 pm = __builtin_bit_cast(f16x8, xm[i]) * __builtin_bit_cast(f16x8, xa[i]);
      *(u32x4*)&sXh1[r * 136 + i * 32 + s * 8] = __builtin_bit_cast(u32x4, pm);
    }
  };
  auto mfmac = [&](int c) {
#pragma unroll
    for (int kk = 0; kk < 4; ++kk) {
      f16x8 af[4];
#pragma unroll
      for (int mi = 0; mi < 4; ++mi)
        af[mi] = *(const f16x8*)&sXh1[(mi * 16 + lm) * 136 + kk * 32 + quad * 8];
#pragma unroll
      for (int tl = 0; tl < 3; ++tl) {
        int n = (w * 3 + tl) * 16 + lm;
        f16x8 bfr = *(const f16x8*)(W1c_t + n * KP + c * BK + kk * 32 + quad * 8);
#pragma unroll
        for (int mi = 0; mi < 4; ++mi)
          acc[mi][tl] = __builtin_amdgcn_mfma_f32_16x16x32_f16(af[mi], bfr, acc[mi][tl], 0, 0, 0);
      }
    }
  };

  loadc(0, xm0, xa0);
#pragma unroll
  for (int c = 0; c < NCH; c += 2) {
    if (c + 1 < NCH) loadc(c + 1, xm1, xa1);   // issue early: spans store+barrier+MFMA of c
    __syncthreads();                            // prev chunk's MFMA done reading sXh1
    storec(xm0, xa0);
    __syncthreads();
    mfmac(c);
    if (c + 2 < NCH) loadc(c + 2, xm0, xa0);
    __syncthreads();
    storec(xm1, xa1);
    __syncthreads();
    mfmac(c + 1);
  }

  // ---- epilogue 1: + bias, relu, h1 -> LDS (stride 200)
  __syncthreads();   // all waves done with staging reads + sBias complete
#pragma unroll
  for (int mi = 0; mi < 4; ++mi)
#pragma unroll
    for (int tl = 0; tl < 3; ++tl) {
      int n = (w * 3 + tl) * 16 + lm;
#pragma unroll
      for (int reg = 0; reg < 4; ++reg) {
        int m = mi * 16 + quad * 4 + reg;
        float v = acc[mi][tl][reg] + h2f(sBias[m * NP + n]);
        v = fmaxf(v, 0.f);
        sXh1[m * 200 + n] = f2h(v);
      }
    }
  __syncthreads();

  // ---- layer 2: h1[64][192] @ W2_t
  f32x4 acc2[4][3];
#pragma unroll
  for (int a = 0; a < 4; ++a)
#pragma unroll
    for (int b = 0; b < 3; ++b) { acc2[a][b].x = 0.f; acc2[a][b].y = 0.f; acc2[a][b].z = 0.f; acc2[a][b].w = 0.f; }
#pragma unroll
  for (int kk = 0; kk < 6; ++kk) {
    f16x8 af[4];
#pragma unroll
    for (int mi = 0; mi < 4; ++mi)
      af[mi] = *(const f16x8*)&sXh1[(mi * 16 + lm) * 200 + kk * 32 + quad * 8];
#pragma unroll
    for (int tl = 0; tl < 3; ++tl) {
      int n = (w * 3 + tl) * 16 + lm;
      f16x8 bfr = *(const f16x8*)(W2_t + n * NP + kk * 32 + quad * 8);
#pragma unroll
      for (int mi = 0; mi < 4; ++mi)
        acc2[mi][tl] = __builtin_amdgcn_mfma_f32_16x16x32_f16(af[mi], bfr, acc2[mi][tl], 0, 0, 0);
    }
  }

  // ---- epilogue 2: + b2, relu, h2 -> sBias region (stride NP)
#pragma unroll
  for (int mi = 0; mi < 4; ++mi)
#pragma unroll
    for (int tl = 0; tl < 3; ++tl) {
      int n = (w * 3 + tl) * 16 + lm;
      float bb = (n < 150) ? b2[n] : 0.f;
#pragma unroll
      for (int reg = 0; reg < 4; ++reg) {
        int m = mi * 16 + quad * 4 + reg;
        float v = acc2[mi][tl][reg] + bb;
        v = fmaxf(v, 0.f);
        sBias[m * NP + n] = f2h(v);
      }
    }
  __syncthreads();

  // ---- layer 3: pairwise = h2 . W3 ; sij = ms_i + ms_j + pairwise + b3
  {
    float sum = 0.f;
#pragma unroll
    for (int j = 0; j < 48; ++j) {
      int n = s * 48 + j;
      if (n < 150) sum += h2f(sBias[r * NP + n]) * W3[n];
    }
    sum += __shfl_xor(sum, 1);
    sum += __shfl_xor(sum, 2);
    if (s == 0) {
      int p = p0 + r;
      if (p < P) out[p] = sScore[r] + sum + b3[0];
    }
  }
}

extern "C" void kernel_launch(void* const* d_in, const int* in_sizes, int n_in,
                              void* d_out, int out_size, void* d_ws, size_t ws_size,
                              hipStream_t stream) {
  (void)n_in; (void)out_size; (void)ws_size;
  const float* g   = (const float*)d_in[0];
  const float* msc = (const float*)d_in[1];
  const float* de  = (const float*)d_in[2];
  const float* ge  = (const float*)d_in[3];
  const float* se  = (const float*)d_in[4];
  const float* W1  = (const float*)d_in[5];
  const float* b1  = (const float*)d_in[6];
  const float* W2  = (const float*)d_in[7];
  const float* b2  = (const float*)d_in[8];
  const float* W3  = (const float*)d_in[9];
  const float* b3  = (const float*)d_in[10];
  const int* mid = (const int*)d_in[11];
  const int* aid = (const int*)d_in[12];
  const int* did = (const int*)d_in[13];
  const int* gid = (const int*)d_in[14];
  const int* sid = (const int*)d_in[15];
  const int N = in_sizes[0] / GI;
  const int P = in_sizes[11];
  float* out = (float*)d_out;

  char* ws = (char*)d_ws;
  size_t off = 0;
  auto alloc = [&](size_t bytes) { char* p = ws + off; off = (off + bytes + 255) & ~(size_t)255; return p; };
  unsigned short* gb     = (unsigned short*)alloc((size_t)N * KP * 2);   // 128 MB f16 copy of g
  unsigned short* AB     = (unsigned short*)alloc((size_t)N * ABW * 2);
  unsigned short* W1ab_t = (unsigned short*)alloc((size_t)ABW * KP * 2);
  unsigned short* W1c_t  = (unsigned short*)alloc((size_t)NP * KP * 2);
  unsigned short* W2_t   = (unsigned short*)alloc((size_t)NP * NP * 2);
  float* projs           = (float*)alloc((size_t)20 * NP * 4);

  const int prep_total = ABW * KP + NP * KP + NP * NP + 20 * NP;
  prep_kernel<<<(prep_total + 255) / 256, 256, 0, stream>>>(W1, W2, b1, de, ge, se,
                                                            W1ab_t, W1c_t, W2_t, projs);
  g2h_kernel<<<(N * (KP / 8) + 255) / 256, 256, 0, stream>>>(g, gb, N);
  ab_kernel<<<(N + 63) / 64, 256, 0, stream>>>(gb, W1ab_t, AB, N);
  pair_kernel<<<(P + 63) / 64, 256, 0, stream>>>(gb, msc, AB, W1c_t, W2_t, projs,
                                                 b2, W3, b3, mid, aid, did, gid, sid,
                                                 out, N, P);
}